// Round 16
// baseline (102.909 us; speedup 1.0000x reference)
//
#include <hip/hip_runtime.h>
#include <math.h>

#define MM 16
#define CC 345
#define MC (MM*CC)   // 5520
#define KTOP 4
// Guard threshold in tc-space (validated R15: absmax unchanged, trigger ~0.5%).
#define GAP_THR 3e-7f
#define NT 256       // 4 waves; wave w owns rows m=4w..4w+3; one block per b

__device__ __forceinline__ float fexp(float x) { return __expf(x); }
__device__ __forceinline__ float flog(float x) { return __logf(x); }

__device__ __forceinline__ float rmax16(float v) {
    #pragma unroll
    for (int off = 8; off; off >>= 1) v = fmaxf(v, __shfl_xor(v, off, 16));
    return v;
}
__device__ __forceinline__ float rmin16(float v) {
    #pragma unroll
    for (int off = 8; off; off >>= 1) v = fminf(v, __shfl_xor(v, off, 16));
    return v;
}
__device__ __forceinline__ float rsum16(float v) {
    #pragma unroll
    for (int off = 8; off; off >>= 1) v += __shfl_xor(v, off, 16);
    return v;
}
__device__ __forceinline__ float rmax64(float v) {
    #pragma unroll
    for (int off = 32; off; off >>= 1) v = fmaxf(v, __shfl_xor(v, off, 64));
    return v;
}
__device__ __forceinline__ float rsum64(float v) {
    #pragma unroll
    for (int off = 32; off; off >>= 1) v += __shfl_xor(v, off, 64);
    return v;
}

__global__ __launch_bounds__(NT)
void ens_main(const float* __restrict__ y, const int* __restrict__ labels,
              float* __restrict__ out, float* __restrict__ partial, int B)
{
    const int tid = threadIdx.x;
    const int w   = tid >> 6;     // wave 0..3, owns m = 4w..4w+3
    const int l   = tid & 63;
    const int b   = blockIdx.x;
    const int lm  = l & 15;       // lane's "m" role in phase 3
    const int mq  = l >> 4;       // 16-lane group id 0..3 (guard path)
    const int g   = l & 15;

    __shared__ float sl[MC + 8];      // logits tile
    __shared__ float sems[CC];        // ems_out
    __shared__ float s_truep[MM], s_epl[MM], s_mx[MM];

    const int label = labels[b];
    const float* yb = y + (size_t)b * MC;

    // ---- Phase 1+2 fused, barrier-free: wave w loads its 4 rows into
    // registers, mirrors them to LDS (for phase 4 + guard), computes
    // softmax stats in-wave. mx is exact (fmax order-independent).
    {
        float v[4][6];
        #pragma unroll
        for (int i = 0; i < 4; ++i) {
            const int m = 4 * w + i;
            const float* row = yb + m * CC;
            float* srow = sl + m * CC;
            #pragma unroll
            for (int r = 0; r < 5; ++r) {
                v[i][r] = row[l + (r << 6)];
                srow[l + (r << 6)] = v[i][r];
            }
            if (l < 25) { v[i][5] = row[320 + l]; srow[320 + l] = v[i][5]; }
            else          v[i][5] = 0.f;
        }
        #pragma unroll
        for (int i = 0; i < 4; ++i) {
            const int m = 4 * w + i;
            float mx = fmaxf(fmaxf(fmaxf(v[i][0], v[i][1]), fmaxf(v[i][2], v[i][3])), v[i][4]);
            mx = fmaxf(mx, (l < 25) ? v[i][5] : -INFINITY);
            mx = rmax64(mx);
            float se = fexp(v[i][0] - mx) + fexp(v[i][1] - mx) + fexp(v[i][2] - mx)
                     + fexp(v[i][3] - mx) + fexp(v[i][4] - mx);
            se += (l < 25) ? fexp(v[i][5] - mx) : 0.f;
            se = rsum64(se);
            if (l == 0) {
                const float lt = yb[m * CC + label];
                s_mx[m]    = mx;                      // exact max, reused by 3b
                s_truep[m] = fexp(lt - mx) / se;      // fast probs[b,m,label]
                s_epl[m]   = -(lt - mx - flog(se));   // -log_softmax[b,m,label]
            }
        }
    }
    __syncthreads();   // #1 — sl + stats ready

    // ---- Phase 3a (R12-verbatim; all 4 waves redundantly, wave-synchronous):
    const float tpv  = s_truep[lm];
    const float eplv = s_epl[lm];
    float mxs = rmax16(tpv);
    float e0  = fexp(tpv - mxs);
    float tc  = e0 / rsum16(e0);                       // true_confs (fast)
    float s1  = fmaxf(rsum16(fabsf(tc)), 1e-12f);
    float wm  = tc / s1;                               // weighted_mat
    int rank = 0;
    #pragma unroll
    for (int j = 0; j < MM; ++j) {
        const float vj = __shfl(tc, j, 16);
        rank += (vj > tc) || (vj == tc && j < lm);
    }
    bool sel = (rank < KTOP);
    const float val4 = rmin16(sel ? tc : INFINITY);    // smallest selected
    const float val5 = rmax16(sel ? -INFINITY : tc);   // largest unselected
    const bool need = (val4 - val5 < GAP_THR);         // wave-uniform, rare

    // ---- Phase 3b (R12-verbatim): guarded rows -> BIT-EXACT round-1 chain:
    // libm expf, strided-16 ascending reads + xor-tree rsum16 (same exact mx),
    // serial ascending denominator, tie-ranked top-4.
    if (need) {
        float tpp4[4];
        #pragma unroll
        for (int i = 0; i < 4; ++i) {
            const int m = i * 4 + mq;
            const float* row = yb + m * CC;
            const float mx = s_mx[m];                  // bitwise-same as phase 2
            float se = 0.f;
            for (int c = g; c < CC; c += 16) se += expf(row[c] - mx);
            se = rsum16(se);
            tpp4[i] = expf(row[label] - mx) / se;
        }
        float tppv = 0.f;
        {
            const int src = (lm & 3) << 4;
            #pragma unroll
            for (int i = 0; i < 4; ++i) {
                const float a_ = __shfl(tpp4[i], src, 64);
                if ((lm >> 2) == i) tppv = a_;
            }
        }
        const float mxx = rmax16(tppv);
        const float ev  = expf(tppv - mxx);
        float ses = 0.f;
        #pragma unroll
        for (int m = 0; m < MM; ++m) ses += __shfl(ev, m, 16);  // serial ascending
        const float tcpv = ev / ses;
        int rk = 0;
        #pragma unroll
        for (int j = 0; j < MM; ++j) {
            const float vj = __shfl(tcpv, j, 16);
            rk += (vj > tcpv) || (vj == tcpv && j < lm);
        }
        sel = (rk < KTOP);
    }

    // ---- Phase 3c (R12-verbatim): finish per-b math
    const float post = sel ? tc : 0.f;
    const float psum = fmaxf(rsum16(fabsf(post)), 1e-12f);
    const float pw   = post / psum;
    const float mw = rmax16(wm);
    const float ex = fexp(wm - mw);
    const float xv = ex / rsum16(ex);
    const float mt = rmax16(tc);
    const float et = fexp(tc - mt);
    const float tv = et / rsum16(et);
    const float childp = eplv * xv;
    const float confp  = fmaxf(xv, 0.f) - xv * tv + flog(1.f + fexp(-fabsf(xv)));
    const float childs = rsum16(childp);
    const float confs  = rsum16(confp);
    if (tid == 0) {
        partial[(size_t)b * 3 + 0] = childs;
        partial[(size_t)b * 3 + 1] = confs;
    }
    if (tid < MM) {
        const size_t off_wm = (size_t)B * CC + 3;
        const size_t off_tc = off_wm + (size_t)B * MM;
        out[off_wm + (size_t)b * MM + tid] = xv;  // wm_soft
        out[off_tc + (size_t)b * MM + tid] = tc;  // true_confs
    }

    // ---- Phase 4: einsum from LDS (no barrier needed: sl covered by #1;
    // weights live in this wave's registers, broadcast per-m via shfl).
    {
        float aa0 = 0.f, ap0 = 0.f, aa1 = 0.f, ap1 = 0.f;
        const int c0 = tid;            // always < 345
        const int c1 = tid + NT;
        const bool act1 = (c1 < CC);
        #pragma unroll
        for (int m = 0; m < MM; ++m) {
            const float wvm = __shfl(wm, m, 16);
            const float pvm = __shfl(pw, m, 16);
            const float x0 = sl[m * CC + c0];
            aa0 = fmaf(x0, wvm, aa0);
            ap0 = fmaf(x0, pvm, ap0);
            if (act1) {
                const float x1 = sl[m * CC + c1];
                aa1 = fmaf(x1, wvm, aa1);
                ap1 = fmaf(x1, pvm, ap1);
            }
        }
        sems[c0] = aa0;
        out[(size_t)b * CC + c0] = ap0;       // ems_out_post
        if (act1) {
            sems[c1] = aa1;
            out[(size_t)b * CC + c1] = ap1;
        }
    }
    __syncthreads();   // #2 — sems ready

    // ---- Phase 5: -log_softmax(ems_out)[label], wave 0 only, in-register.
    if (w == 0) {
        float q[6];
        float m5 = -INFINITY;
        #pragma unroll
        for (int r = 0; r < 6; ++r) {
            const int c = l + (r << 6);
            q[r] = (c < CC) ? sems[c] : -INFINITY;
            m5 = fmaxf(m5, q[r]);
        }
        m5 = rmax64(m5);
        float se5 = 0.f;
        #pragma unroll
        for (int r = 0; r < 6; ++r) {
            const int c = l + (r << 6);
            if (c < CC) se5 += fexp(q[r] - m5);
        }
        se5 = rsum64(se5);
        if (l == 0)
            partial[(size_t)b * 3 + 2] = -(sems[label] - m5 - flog(se5));
    }
}

// Deterministic fixed-order reduction of per-b partials -> the 3 scalar losses.
__global__ __launch_bounds__(256)
void ens_reduce(const float* __restrict__ partial, float* __restrict__ out, int B)
{
    const int tid = threadIdx.x;
    double c = 0.0, f = 0.0, e = 0.0;
    for (int i = tid; i < B; i += 256) {
        c += (double)partial[(size_t)i * 3 + 0];
        f += (double)partial[(size_t)i * 3 + 1];
        e += (double)partial[(size_t)i * 3 + 2];
    }
    #pragma unroll
    for (int off = 32; off; off >>= 1) {
        c += __shfl_xor(c, off);
        f += __shfl_xor(f, off);
        e += __shfl_xor(e, off);
    }
    __shared__ double rc[4], rf[4], re[4];
    if ((tid & 63) == 0) { rc[tid >> 6] = c; rf[tid >> 6] = f; re[tid >> 6] = e; }
    __syncthreads();
    if (tid == 0) {
        const double cs = rc[0] + rc[1] + rc[2] + rc[3];
        const double fs = rf[0] + rf[1] + rf[2] + rf[3];
        const double es = re[0] + re[1] + re[2] + re[3];
        const size_t base = (size_t)B * CC;
        out[base + 0] = (float)(cs / (double)((size_t)B * MM));  // child_loss
        out[base + 1] = (float)(fs / (double)((size_t)B * MM));  // confidence_loss
        out[base + 2] = (float)(es / (double)B);                 // ensemble_loss
    }
}

extern "C" void kernel_launch(void* const* d_in, const int* in_sizes, int n_in,
                              void* d_out, int out_size, void* d_ws, size_t ws_size,
                              hipStream_t stream)
{
    const float* y      = (const float*)d_in[0];
    const int*   labels = (const int*)d_in[1];
    const int    B      = in_sizes[1];      // 8192
    float* out     = (float*)d_out;
    float* partial = (float*)d_ws;          // B*3 floats = 96 KB

    ens_main<<<dim3(B), dim3(NT), 0, stream>>>(y, labels, out, partial, B);
    ens_reduce<<<dim3(1), dim3(256), 0, stream>>>(partial, out, B);
}